// Round 4
// baseline (1677.704 us; speedup 1.0000x reference)
//
#include <hip/hip_runtime.h>

constexpr int NN = 100000;   // nodes
constexpr int DI = 256;      // in features
constexpr int DO = 128;      // out features
constexpr int NE = 1600000;  // edges

constexpr int BROWS = 128;                        // rows per bucket
constexpr int NBK   = (NN + BROWS - 1) / BROWS;   // 782 buckets
constexpr int SROW  = 136;                        // LDS acc row stride (floats)
constexpr int TILE  = 8192;                       // edges per partition block

typedef __bf16 bf16x8 __attribute__((ext_vector_type(8)));
typedef float  f32x4  __attribute__((ext_vector_type(4)));

__device__ inline unsigned short f2bf(float f) {
    union { float f; unsigned u; } v; v.f = f;
    return (unsigned short)((v.u + 0x7FFF + ((v.u >> 16) & 1)) >> 16);
}
__device__ inline float bf2f(unsigned u16) {
    union { unsigned u; float f; } v; v.u = u16 << 16;
    return v.f;
}

// ---------------- W transpose: W[256][128] f32 -> Wt[128][256] bf16 ----------
__global__ __launch_bounds__(256)
void wt_kernel(const float* __restrict__ W, unsigned short* __restrict__ Wt) {
    __shared__ float t[32][33];
    const int tx = threadIdx.x & 31, ty = threadIdx.x >> 5;  // ty 0..7
    const int k0 = (blockIdx.x >> 2) * 32, n0 = (blockIdx.x & 3) * 32;
#pragma unroll
    for (int i = 0; i < 32; i += 8)
        t[ty + i][tx] = W[(size_t)(k0 + ty + i) * DO + n0 + tx];
    __syncthreads();
#pragma unroll
    for (int i = 0; i < 32; i += 8)
        Wt[(size_t)(n0 + ty + i) * DI + k0 + tx] = f2bf(t[tx][ty + i]);
}

// ---------------- GEMM: h = bf16( (x*mask) @ W ), MFMA ----------------
__global__ __launch_bounds__(256)
void gemm_kernel(const float* __restrict__ x, const float* __restrict__ mask,
                 const unsigned short* __restrict__ Wt,
                 unsigned short* __restrict__ h) {
    __shared__ unsigned short As[128][72];
    __shared__ unsigned short Bs[128][72];
    const int tid  = threadIdx.x;
    const int lane = tid & 63;
    const int w    = tid >> 6;
    const int m0   = blockIdx.x * 128;
    const int mw   = w * 32;
    const int l15  = lane & 15;
    const int l4   = lane >> 4;

    f32x4 acc[2][8];
#pragma unroll
    for (int rt = 0; rt < 2; ++rt)
#pragma unroll
        for (int ct = 0; ct < 8; ++ct) acc[rt][ct] = (f32x4){0.f, 0.f, 0.f, 0.f};

    for (int kc = 0; kc < DI; kc += 64) {
        {
            const int kl = (tid & 15) * 4;
#pragma unroll
            for (int p = 0; p < 8; ++p) {
                const int r = p * 16 + (tid >> 4);
                float4 xv = make_float4(0.f, 0.f, 0.f, 0.f);
                float4 mv = make_float4(0.f, 0.f, 0.f, 0.f);
                if (m0 + r < NN) {
                    xv = *(const float4*)(x    + (size_t)(m0 + r) * DI + kc + kl);
                    mv = *(const float4*)(mask + (size_t)(m0 + r) * DI + kc + kl);
                }
                ushort4 pk;
                pk.x = f2bf(xv.x * mv.x); pk.y = f2bf(xv.y * mv.y);
                pk.z = f2bf(xv.z * mv.z); pk.w = f2bf(xv.w * mv.w);
                *(ushort4*)&As[r][kl] = pk;
            }
        }
        {
            const int kl = (tid & 7) * 8;
#pragma unroll
            for (int p = 0; p < 4; ++p) {
                const int n = p * 32 + (tid >> 3);
                *(uint4*)&Bs[n][kl] =
                    *(const uint4*)(Wt + (size_t)n * DI + kc + kl);
            }
        }
        __syncthreads();
#pragma unroll
        for (int ks = 0; ks < 2; ++ks) {
            const int ko = ks * 32 + l4 * 8;
            bf16x8 a0 = *(const bf16x8*)&As[mw + l15][ko];
            bf16x8 a1 = *(const bf16x8*)&As[mw + 16 + l15][ko];
#pragma unroll
            for (int ct = 0; ct < 8; ++ct) {
                bf16x8 b = *(const bf16x8*)&Bs[ct * 16 + l15][ko];
                acc[0][ct] = __builtin_amdgcn_mfma_f32_16x16x32_bf16(a0, b, acc[0][ct], 0, 0, 0);
                acc[1][ct] = __builtin_amdgcn_mfma_f32_16x16x32_bf16(a1, b, acc[1][ct], 0, 0, 0);
            }
        }
        __syncthreads();
    }
#pragma unroll
    for (int rt = 0; rt < 2; ++rt)
#pragma unroll
        for (int ct = 0; ct < 8; ++ct)
#pragma unroll
            for (int reg = 0; reg < 4; ++reg) {
                const int row = m0 + mw + rt * 16 + l4 * 4 + reg;
                if (row < NN)
                    h[(size_t)row * DO + ct * 16 + l15] = f2bf(acc[rt][ct][reg]);
            }
}

// ---------------- bucket histogram (LDS-staged) ----------------
__global__ __launch_bounds__(256)
void bhist_kernel(const int* __restrict__ erow, int* __restrict__ bcnt) {
    __shared__ int cnt[NBK];
    const int t = threadIdx.x;
    for (int k = t; k < NBK; k += 256) cnt[k] = 0;
    __syncthreads();
    for (int e = blockIdx.x * 256 + t; e < NE; e += 256 * 256)
        atomicAdd(&cnt[erow[e] >> 7], 1);
    __syncthreads();
    for (int k = t; k < NBK; k += 256) {
        const int c = cnt[k];
        if (c) atomicAdd(&bcnt[k], c);
    }
}

// ---------------- bucket scan (782 elems, single block) ----------------
__global__ __launch_bounds__(1024)
void bscan_kernel(const int* __restrict__ bcnt, int* __restrict__ bstart,
                  int* __restrict__ bcursor) {
    __shared__ int wsum[16];
    const int t = threadIdx.x, lane = t & 63, wid = t >> 6;
    const int c = (t < NBK) ? bcnt[t] : 0;
    int v = c;
#pragma unroll
    for (int off = 1; off < 64; off <<= 1) {
        const int n = __shfl_up(v, off, 64);
        if (lane >= off) v += n;
    }
    if (lane == 63) wsum[wid] = v;
    __syncthreads();
    int p = 0;
#pragma unroll
    for (int i = 0; i < 16; ++i)
        if (i < wid) p += wsum[i];
    const int excl = p + v - c;
    if (t <= NBK) bstart[t] = excl;   // bstart[NBK] = NE
    if (t < NBK)  bcursor[t] = excl;
}

// ---------------- partition: edges -> bucket-contiguous packed list --------
// Per-tile LDS histogram -> one global cursor bump per (block,bucket) ->
// writes cluster into contiguous per-bucket ranges (L2 merges into lines).
__global__ __launch_bounds__(256)
void part_kernel(const int* __restrict__ erow, const int* __restrict__ ecol,
                 const float* __restrict__ ew, int* __restrict__ bcursor,
                 int2* __restrict__ csr) {
    __shared__ int cnt[NBK];
    __shared__ int base[NBK];
    const int t  = threadIdx.x;
    const int e0 = blockIdx.x * TILE;
    for (int k = t; k < NBK; k += 256) cnt[k] = 0;
    __syncthreads();
    for (int k = 0; k < TILE; k += 256) {
        const int e = e0 + k + t;
        if (e < NE) atomicAdd(&cnt[erow[e] >> 7], 1);
    }
    __syncthreads();
    for (int k = t; k < NBK; k += 256) {
        const int c = cnt[k];
        base[k] = c ? atomicAdd(&bcursor[k], c) : 0;
        cnt[k] = 0;
    }
    __syncthreads();
    for (int k = 0; k < TILE; k += 256) {
        const int e = e0 + k + t;
        if (e < NE) {
            const int row = erow[e];
            const int bk  = row >> 7;
            const int pos = atomicAdd(&cnt[bk], 1);
            int2 v;
            v.x = ((row & 127) << 17) | ecol[e];   // col < 2^17
            v.y = __float_as_int(ew[e]);
            csr[base[bk] + pos] = v;
        }
    }
}

// ---------------- bucket accumulate + ReLU ----------------
// One block per 128-row bucket; fp32 accumulator in LDS (swizzled:
// feat f of row r at acc[r*136 + (f&7)*16 + (f>>3)] -> ~2-way ds conflicts).
__global__ __launch_bounds__(256)
void accum_kernel(const unsigned short* __restrict__ h,
                  const int* __restrict__ bstart,
                  const int2* __restrict__ csr, float* __restrict__ out) {
    __shared__ float acc[BROWS * SROW];
    const int b = blockIdx.x;
    const int t = threadIdx.x;
    float4* a4 = (float4*)acc;
    for (int k = t; k < BROWS * SROW / 4; k += 256)
        a4[k] = make_float4(0.f, 0.f, 0.f, 0.f);
    __syncthreads();

    const int start = bstart[b], end = bstart[b + 1];
    const int lane = t & 15, eg = t >> 4;   // 16 edge-groups x 16 lanes

    for (int j = start + eg; j < end; j += 16) {
        const int2 cw = csr[j];
        const int   rowoff = ((unsigned)cw.x) >> 17;
        const int   col    = cw.x & 0x1FFFF;
        const float w      = __int_as_float(cw.y);
        const uint4 q = *(const uint4*)(h + (size_t)col * DO + lane * 8);
        const unsigned* u = (const unsigned*)&q;
        float* ar = acc + rowoff * SROW + lane;
#pragma unroll
        for (int i = 0; i < 4; ++i) {
            atomicAdd(ar + 32 * i,      w * bf2f(u[i] & 0xFFFF));
            atomicAdd(ar + 32 * i + 16, w * bf2f(u[i] >> 16));
        }
    }
    __syncthreads();

    const int row0 = b * BROWS;
#pragma unroll
    for (int rp = 0; rp < 8; ++rp) {
        const int r  = rp * 16 + eg;
        const int gr = row0 + r;
        if (gr < NN) {
            float v[8];
#pragma unroll
            for (int i = 0; i < 8; ++i)
                v[i] = fmaxf(acc[r * SROW + i * 16 + lane], 0.f);
            float* op = out + (size_t)gr * DO + lane * 8;
            *(float4*)(op + 0) = make_float4(v[0], v[1], v[2], v[3]);
            *(float4*)(op + 4) = make_float4(v[4], v[5], v[6], v[7]);
        }
    }
}

extern "C" void kernel_launch(void* const* d_in, const int* in_sizes, int n_in,
                              void* d_out, int out_size, void* d_ws, size_t ws_size,
                              hipStream_t stream) {
    const float* x    = (const float*)d_in[0];
    const float* mask = (const float*)d_in[1];
    const float* W    = (const float*)d_in[2];
    const int*   erow = (const int*)d_in[3];
    const int*   ecol = (const int*)d_in[4];
    const float* ew   = (const float*)d_in[5];
    float* out = (float*)d_out;

    char* p = (char*)d_ws;
    unsigned short* h  = (unsigned short*)p;  p += (size_t)NN * DO * 2;   // 25.6 MB
    unsigned short* Wt = (unsigned short*)p;  p += (size_t)DO * DI * 2;   // 64 KB
    int* bcnt    = (int*)p;                   p += 3200;
    int* bstart  = (int*)p;                   p += 3200;
    int* bcursor = (int*)p;                   p += 3200;
    int2* csr    = (int2*)p;                  // 12.8 MB

    hipMemsetAsync(bcnt, 0, NBK * sizeof(int), stream);

    wt_kernel<<<32, 256, 0, stream>>>(W, Wt);
    gemm_kernel<<<(NN + 127) / 128, 256, 0, stream>>>(x, mask, Wt, h);
    bhist_kernel<<<256, 256, 0, stream>>>(erow, bcnt);
    bscan_kernel<<<1, 1024, 0, stream>>>(bcnt, bstart, bcursor);
    part_kernel<<<(NE + TILE - 1) / TILE, 256, 0, stream>>>(erow, ecol, ew,
                                                            bcursor, csr);
    accum_kernel<<<NBK, 256, 0, stream>>>(h, bstart, csr, out);
}

// Round 5
// 413.574 us; speedup vs baseline: 4.0566x; 4.0566x over previous
//
#include <hip/hip_runtime.h>

constexpr int NN = 100000;   // nodes
constexpr int DI = 256;      // in features
constexpr int DO = 128;      // out features
constexpr int NE = 1600000;  // edges

constexpr int BROWS = 128;                        // rows per bucket
constexpr int NBK   = (NN + BROWS - 1) / BROWS;   // 782 buckets
constexpr int TILE  = 8192;                       // edges per partition block
constexpr int CAP   = 2688;                       // max edges per bucket (mean 2048, sd 45)

typedef __bf16 bf16x8 __attribute__((ext_vector_type(8)));
typedef float  f32x4  __attribute__((ext_vector_type(4)));

__device__ inline unsigned short f2bf(float f) {
    union { float f; unsigned u; } v; v.f = f;
    return (unsigned short)((v.u + 0x7FFF + ((v.u >> 16) & 1)) >> 16);
}
__device__ inline float bf2f(unsigned u16) {
    union { unsigned u; float f; } v; v.u = u16 << 16;
    return v.f;
}

// ---------------- W transpose: W[256][128] f32 -> Wt[128][256] bf16 ----------
__global__ __launch_bounds__(256)
void wt_kernel(const float* __restrict__ W, unsigned short* __restrict__ Wt) {
    __shared__ float t[32][33];
    const int tx = threadIdx.x & 31, ty = threadIdx.x >> 5;
    const int k0 = (blockIdx.x >> 2) * 32, n0 = (blockIdx.x & 3) * 32;
#pragma unroll
    for (int i = 0; i < 32; i += 8)
        t[ty + i][tx] = W[(size_t)(k0 + ty + i) * DO + n0 + tx];
    __syncthreads();
#pragma unroll
    for (int i = 0; i < 32; i += 8)
        Wt[(size_t)(n0 + ty + i) * DI + k0 + tx] = f2bf(t[tx][ty + i]);
}

// ---------------- GEMM: h = bf16( (x*mask) @ W ), MFMA ----------------
__global__ __launch_bounds__(256)
void gemm_kernel(const float* __restrict__ x, const float* __restrict__ mask,
                 const unsigned short* __restrict__ Wt,
                 unsigned short* __restrict__ h) {
    __shared__ unsigned short As[128][72];
    __shared__ unsigned short Bs[128][72];
    const int tid  = threadIdx.x;
    const int lane = tid & 63;
    const int w    = tid >> 6;
    const int m0   = blockIdx.x * 128;
    const int mw   = w * 32;
    const int l15  = lane & 15;
    const int l4   = lane >> 4;

    f32x4 acc[2][8];
#pragma unroll
    for (int rt = 0; rt < 2; ++rt)
#pragma unroll
        for (int ct = 0; ct < 8; ++ct) acc[rt][ct] = (f32x4){0.f, 0.f, 0.f, 0.f};

    for (int kc = 0; kc < DI; kc += 64) {
        {
            const int kl = (tid & 15) * 4;
#pragma unroll
            for (int p = 0; p < 8; ++p) {
                const int r = p * 16 + (tid >> 4);
                float4 xv = make_float4(0.f, 0.f, 0.f, 0.f);
                float4 mv = make_float4(0.f, 0.f, 0.f, 0.f);
                if (m0 + r < NN) {
                    xv = *(const float4*)(x    + (size_t)(m0 + r) * DI + kc + kl);
                    mv = *(const float4*)(mask + (size_t)(m0 + r) * DI + kc + kl);
                }
                ushort4 pk;
                pk.x = f2bf(xv.x * mv.x); pk.y = f2bf(xv.y * mv.y);
                pk.z = f2bf(xv.z * mv.z); pk.w = f2bf(xv.w * mv.w);
                *(ushort4*)&As[r][kl] = pk;
            }
        }
        {
            const int kl = (tid & 7) * 8;
#pragma unroll
            for (int p = 0; p < 4; ++p) {
                const int n = p * 32 + (tid >> 3);
                *(uint4*)&Bs[n][kl] =
                    *(const uint4*)(Wt + (size_t)n * DI + kc + kl);
            }
        }
        __syncthreads();
#pragma unroll
        for (int ks = 0; ks < 2; ++ks) {
            const int ko = ks * 32 + l4 * 8;
            bf16x8 a0 = *(const bf16x8*)&As[mw + l15][ko];
            bf16x8 a1 = *(const bf16x8*)&As[mw + 16 + l15][ko];
#pragma unroll
            for (int ct = 0; ct < 8; ++ct) {
                bf16x8 b = *(const bf16x8*)&Bs[ct * 16 + l15][ko];
                acc[0][ct] = __builtin_amdgcn_mfma_f32_16x16x32_bf16(a0, b, acc[0][ct], 0, 0, 0);
                acc[1][ct] = __builtin_amdgcn_mfma_f32_16x16x32_bf16(a1, b, acc[1][ct], 0, 0, 0);
            }
        }
        __syncthreads();
    }
#pragma unroll
    for (int rt = 0; rt < 2; ++rt)
#pragma unroll
        for (int ct = 0; ct < 8; ++ct)
#pragma unroll
            for (int reg = 0; reg < 4; ++reg) {
                const int row = m0 + mw + rt * 16 + l4 * 4 + reg;
                if (row < NN)
                    h[(size_t)row * DO + ct * 16 + l15] = f2bf(acc[rt][ct][reg]);
            }
}

// ---------------- bucket histogram (LDS-staged) ----------------
__global__ __launch_bounds__(256)
void bhist_kernel(const int* __restrict__ erow, int* __restrict__ bcnt) {
    __shared__ int cnt[NBK];
    const int t = threadIdx.x;
    for (int k = t; k < NBK; k += 256) cnt[k] = 0;
    __syncthreads();
    for (int e = blockIdx.x * 256 + t; e < NE; e += 256 * 256)
        atomicAdd(&cnt[erow[e] >> 7], 1);
    __syncthreads();
    for (int k = t; k < NBK; k += 256) {
        const int c = cnt[k];
        if (c) atomicAdd(&bcnt[k], c);
    }
}

// ---------------- bucket scan (782 elems, single block) ----------------
__global__ __launch_bounds__(1024)
void bscan_kernel(const int* __restrict__ bcnt, int* __restrict__ bstart,
                  int* __restrict__ bcursor) {
    __shared__ int wsum[16];
    const int t = threadIdx.x, lane = t & 63, wid = t >> 6;
    const int c = (t < NBK) ? bcnt[t] : 0;
    int v = c;
#pragma unroll
    for (int off = 1; off < 64; off <<= 1) {
        const int n = __shfl_up(v, off, 64);
        if (lane >= off) v += n;
    }
    if (lane == 63) wsum[wid] = v;
    __syncthreads();
    int p = 0;
#pragma unroll
    for (int i = 0; i < 16; ++i)
        if (i < wid) p += wsum[i];
    const int excl = p + v - c;
    if (t <= NBK) bstart[t] = excl;   // bstart[NBK] = NE
    if (t < NBK)  bcursor[t] = excl;
}

// ---------------- partition: edges -> bucket-contiguous packed list --------
__global__ __launch_bounds__(256)
void part_kernel(const int* __restrict__ erow, const int* __restrict__ ecol,
                 const float* __restrict__ ew, int* __restrict__ bcursor,
                 int2* __restrict__ csr) {
    __shared__ int cnt[NBK];
    __shared__ int base[NBK];
    const int t  = threadIdx.x;
    const int e0 = blockIdx.x * TILE;
    for (int k = t; k < NBK; k += 256) cnt[k] = 0;
    __syncthreads();
    for (int k = 0; k < TILE; k += 256) {
        const int e = e0 + k + t;
        if (e < NE) atomicAdd(&cnt[erow[e] >> 7], 1);
    }
    __syncthreads();
    for (int k = t; k < NBK; k += 256) {
        const int c = cnt[k];
        base[k] = c ? atomicAdd(&bcursor[k], c) : 0;
        cnt[k] = 0;
    }
    __syncthreads();
    for (int k = 0; k < TILE; k += 256) {
        const int e = e0 + k + t;
        if (e < NE) {
            const int row = erow[e];
            const int bk  = row >> 7;
            const int pos = atomicAdd(&cnt[bk], 1);
            int2 v;
            v.x = ((row & 127) << 17) | ecol[e];   // col < 2^17
            v.y = __float_as_int(ew[e]);
            csr[base[bk] + pos] = v;
        }
    }
}

// ---------------- bucket gather: in-LDS counting sort + register gather ----
// One block per bucket. Sort bucket's edges by row in LDS, then 16 lanes/row
// register-accumulate w*h[col], fused ReLU, one contiguous write per row.
__global__ __launch_bounds__(256)
void bgather_kernel(const unsigned short* __restrict__ h,
                    const int* __restrict__ bstart,
                    const int2* __restrict__ csr, float* __restrict__ out) {
    __shared__ int2 se[CAP];            // sorted edges
    __shared__ int  s_cnt[BROWS];       // histogram -> cursor
    __shared__ int  s_start[BROWS + 1];
    __shared__ int  wtot;
    const int b = blockIdx.x, t = threadIdx.x;
    const int start = bstart[b], n = bstart[b + 1] - start;

    if (t < BROWS) s_cnt[t] = 0;
    __syncthreads();
    // pass 1: histogram by row-offset
    for (int j = t; j < n; j += 256)
        atomicAdd(&s_cnt[((unsigned)csr[start + j].x) >> 17], 1);
    __syncthreads();
    // scan 128 bins (2 waves participate meaningfully)
    const int lane = t & 63;
    int c = 0;
    if (t < BROWS) c = s_cnt[t];
    int v = c;
#pragma unroll
    for (int off = 1; off < 64; off <<= 1) {
        const int nn = __shfl_up(v, off, 64);
        if (lane >= off) v += nn;
    }
    if (t == 63) wtot = v;
    __syncthreads();
    if (t < BROWS) {
        const int excl = v - c + (t >= 64 ? wtot : 0);
        s_start[t] = excl;
        s_cnt[t]   = excl;   // reuse as scatter cursor
    }
    if (t == 0) s_start[BROWS] = n;
    __syncthreads();
    // pass 2: scatter into sorted order
    for (int j = t; j < n; j += 256) {
        const int2 cw = csr[start + j];
        const int  pos = atomicAdd(&s_cnt[((unsigned)cw.x) >> 17], 1);
        se[pos] = cw;
    }
    __syncthreads();

    // gather: group g (of 16) handles rows g, g+16, ...; lane owns 8 feats
    const int l16 = t & 15, g = t >> 4;
    const int row0 = b * BROWS;
#pragma unroll
    for (int rp = 0; rp < 8; ++rp) {
        const int r  = rp * 16 + g;
        const int gr = row0 + r;
        const int rs = s_start[r], re = s_start[r + 1];
        float acc[8];
#pragma unroll
        for (int i = 0; i < 8; ++i) acc[i] = 0.f;
        int j = rs;
        for (; j + 2 <= re; j += 2) {
            const int2 cw0 = se[j], cw1 = se[j + 1];
            const float w0 = __int_as_float(cw0.y);
            const float w1 = __int_as_float(cw1.y);
            const uint4 q0 = *(const uint4*)(h + (size_t)(cw0.x & 0x1FFFF) * DO + l16 * 8);
            const uint4 q1 = *(const uint4*)(h + (size_t)(cw1.x & 0x1FFFF) * DO + l16 * 8);
            const unsigned* u0 = (const unsigned*)&q0;
            const unsigned* u1 = (const unsigned*)&q1;
#pragma unroll
            for (int i = 0; i < 4; ++i) {
                acc[2 * i + 0] += w0 * bf2f(u0[i] & 0xFFFF) + w1 * bf2f(u1[i] & 0xFFFF);
                acc[2 * i + 1] += w0 * bf2f(u0[i] >> 16)    + w1 * bf2f(u1[i] >> 16);
            }
        }
        if (j < re) {
            const int2 cw = se[j];
            const float w = __int_as_float(cw.y);
            const uint4 q = *(const uint4*)(h + (size_t)(cw.x & 0x1FFFF) * DO + l16 * 8);
            const unsigned* u = (const unsigned*)&q;
#pragma unroll
            for (int i = 0; i < 4; ++i) {
                acc[2 * i + 0] += w * bf2f(u[i] & 0xFFFF);
                acc[2 * i + 1] += w * bf2f(u[i] >> 16);
            }
        }
        if (gr < NN) {
            float* op = out + (size_t)gr * DO + l16 * 8;
            *(float4*)(op + 0) = make_float4(fmaxf(acc[0], 0.f), fmaxf(acc[1], 0.f),
                                             fmaxf(acc[2], 0.f), fmaxf(acc[3], 0.f));
            *(float4*)(op + 4) = make_float4(fmaxf(acc[4], 0.f), fmaxf(acc[5], 0.f),
                                             fmaxf(acc[6], 0.f), fmaxf(acc[7], 0.f));
        }
    }
}

extern "C" void kernel_launch(void* const* d_in, const int* in_sizes, int n_in,
                              void* d_out, int out_size, void* d_ws, size_t ws_size,
                              hipStream_t stream) {
    const float* x    = (const float*)d_in[0];
    const float* mask = (const float*)d_in[1];
    const float* W    = (const float*)d_in[2];
    const int*   erow = (const int*)d_in[3];
    const int*   ecol = (const int*)d_in[4];
    const float* ew   = (const float*)d_in[5];
    float* out = (float*)d_out;

    char* p = (char*)d_ws;
    unsigned short* h  = (unsigned short*)p;  p += (size_t)NN * DO * 2;   // 25.6 MB
    unsigned short* Wt = (unsigned short*)p;  p += (size_t)DO * DI * 2;   // 64 KB
    int* bcnt    = (int*)p;                   p += 3200;
    int* bstart  = (int*)p;                   p += 3200;
    int* bcursor = (int*)p;                   p += 3200;
    int2* csr    = (int2*)p;                  // 12.8 MB

    hipMemsetAsync(bcnt, 0, NBK * sizeof(int), stream);

    wt_kernel<<<32, 256, 0, stream>>>(W, Wt);
    gemm_kernel<<<(NN + 127) / 128, 256, 0, stream>>>(x, mask, Wt, h);
    bhist_kernel<<<256, 256, 0, stream>>>(erow, bcnt);
    bscan_kernel<<<1, 1024, 0, stream>>>(bcnt, bstart, bcursor);
    part_kernel<<<(NE + TILE - 1) / TILE, 256, 0, stream>>>(erow, ecol, ew,
                                                            bcursor, csr);
    bgather_kernel<<<NBK, 256, 0, stream>>>(h, bstart, csr, out);
}

// Round 6
// 389.641 us; speedup vs baseline: 4.3058x; 1.0614x over previous
//
#include <hip/hip_runtime.h>

constexpr int NN = 100000;   // nodes
constexpr int DI = 256;      // in features
constexpr int DO = 128;      // out features
constexpr int NE = 1600000;  // edges

constexpr int BROWS = 128;                        // rows per bucket
constexpr int NBK   = (NN + BROWS - 1) / BROWS;   // 782 buckets
constexpr int TILE  = 8192;                       // edges per partition block
constexpr int CAP   = 2688;                       // slots per bucket (mean 2046, sd ~45)

typedef __bf16 bf16x8 __attribute__((ext_vector_type(8)));
typedef float  f32x4  __attribute__((ext_vector_type(4)));

__device__ inline unsigned short f2bf(float f) {
    union { float f; unsigned u; } v; v.f = f;
    return (unsigned short)((v.u + 0x7FFF + ((v.u >> 16) & 1)) >> 16);
}
__device__ inline float bf2f(unsigned u16) {
    union { unsigned u; float f; } v; v.u = u16 << 16;
    return v.f;
}

// ---------------- W transpose: W[256][128] f32 -> Wt[128][256] bf16 ----------
__global__ __launch_bounds__(256)
void wt_kernel(const float* __restrict__ W, unsigned short* __restrict__ Wt) {
    __shared__ float t[32][33];
    const int tx = threadIdx.x & 31, ty = threadIdx.x >> 5;
    const int k0 = (blockIdx.x >> 2) * 32, n0 = (blockIdx.x & 3) * 32;
#pragma unroll
    for (int i = 0; i < 32; i += 8)
        t[ty + i][tx] = W[(size_t)(k0 + ty + i) * DO + n0 + tx];
    __syncthreads();
#pragma unroll
    for (int i = 0; i < 32; i += 8)
        Wt[(size_t)(n0 + ty + i) * DI + k0 + tx] = f2bf(t[tx][ty + i]);
}

// ---------------- GEMM: h = bf16( (x*mask) @ W ), MFMA, prefetch ------------
// 64-row tiles -> 1563 blocks (6/CU available, 5 resident at 27.6 KB LDS).
// Register prefetch of next K-tile overlaps HBM loads with MFMA.
__global__ __launch_bounds__(256)
void gemm_kernel(const float* __restrict__ x, const float* __restrict__ mask,
                 const unsigned short* __restrict__ Wt,
                 unsigned short* __restrict__ h) {
    __shared__ unsigned short As[64][72];
    __shared__ unsigned short Bs[128][72];
    const int tid  = threadIdx.x;
    const int lane = tid & 63;
    const int w    = tid >> 6;          // wave 0..3
    const int m0   = blockIdx.x * 64;
    const int mw   = w * 16;            // wave's 16-row slice
    const int l15  = lane & 15;
    const int l4   = lane >> 4;

    f32x4 acc[8];
#pragma unroll
    for (int ct = 0; ct < 8; ++ct) acc[ct] = (f32x4){0.f, 0.f, 0.f, 0.f};

    const int lr = tid >> 4;         // 0..15: row within 16-row group
    const int lk = (tid & 15) * 4;   // 0..60: k offset (float4)

    float4 xv[4], mv[4];
    const float4 z4 = make_float4(0.f, 0.f, 0.f, 0.f);

    // prefetch kc = 0
#pragma unroll
    for (int p = 0; p < 4; ++p) {
        const int r = m0 + p * 16 + lr;
        if (r < NN) {
            xv[p] = *(const float4*)(x    + (size_t)r * DI + lk);
            mv[p] = *(const float4*)(mask + (size_t)r * DI + lk);
        } else { xv[p] = z4; mv[p] = z4; }
    }

    for (int kc = 0; kc < DI; kc += 64) {
        __syncthreads();   // prev MFMA done reading LDS
        // store prefetched A (convert to bf16)
#pragma unroll
        for (int p = 0; p < 4; ++p) {
            ushort4 pk;
            pk.x = f2bf(xv[p].x * mv[p].x); pk.y = f2bf(xv[p].y * mv[p].y);
            pk.z = f2bf(xv[p].z * mv[p].z); pk.w = f2bf(xv[p].w * mv[p].w);
            *(ushort4*)&As[p * 16 + lr][lk] = pk;
        }
        // stage B (L2-hot, 16 KB)
        {
            const int kl = (tid & 7) * 8;
#pragma unroll
            for (int p = 0; p < 4; ++p) {
                const int n = p * 32 + (tid >> 3);
                *(uint4*)&Bs[n][kl] =
                    *(const uint4*)(Wt + (size_t)n * DI + kc + kl);
            }
        }
        // prefetch next K-tile (overlaps with MFMA below)
        if (kc + 64 < DI) {
#pragma unroll
            for (int p = 0; p < 4; ++p) {
                const int r = m0 + p * 16 + lr;
                if (r < NN) {
                    xv[p] = *(const float4*)(x    + (size_t)r * DI + kc + 64 + lk);
                    mv[p] = *(const float4*)(mask + (size_t)r * DI + kc + 64 + lk);
                } else { xv[p] = z4; mv[p] = z4; }
            }
        }
        __syncthreads();
#pragma unroll
        for (int ks = 0; ks < 2; ++ks) {
            const int ko = ks * 32 + l4 * 8;
            const bf16x8 a0 = *(const bf16x8*)&As[mw + l15][ko];
#pragma unroll
            for (int ct = 0; ct < 8; ++ct) {
                const bf16x8 b = *(const bf16x8*)&Bs[ct * 16 + l15][ko];
                acc[ct] = __builtin_amdgcn_mfma_f32_16x16x32_bf16(a0, b, acc[ct], 0, 0, 0);
            }
        }
    }
    // epilogue: D[row = l4*4+reg][col = l15]
#pragma unroll
    for (int ct = 0; ct < 8; ++ct)
#pragma unroll
        for (int reg = 0; reg < 4; ++reg) {
            const int row = m0 + mw + l4 * 4 + reg;
            if (row < NN)
                h[(size_t)row * DO + ct * 16 + l15] = f2bf(acc[ct][reg]);
        }
}

// ---------------- partition: edges -> fixed-slot bucket lists ---------------
// csr[b*CAP + i]; global bcnt is both cursor and final per-bucket count.
__global__ __launch_bounds__(256)
void part_kernel(const int* __restrict__ erow, const int* __restrict__ ecol,
                 const float* __restrict__ ew, int* __restrict__ bcnt,
                 int2* __restrict__ csr) {
    __shared__ int cnt[NBK];
    __shared__ int base[NBK];
    const int t  = threadIdx.x;
    const int e0 = blockIdx.x * TILE;
    for (int k = t; k < NBK; k += 256) cnt[k] = 0;
    __syncthreads();
    for (int k = 0; k < TILE; k += 256) {
        const int e = e0 + k + t;
        if (e < NE) atomicAdd(&cnt[erow[e] >> 7], 1);
    }
    __syncthreads();
    for (int k = t; k < NBK; k += 256) {
        const int c = cnt[k];
        base[k] = c ? atomicAdd(&bcnt[k], c) : 0;
        cnt[k] = 0;
    }
    __syncthreads();
    for (int k = 0; k < TILE; k += 256) {
        const int e = e0 + k + t;
        if (e < NE) {
            const int row = erow[e];
            const int bk  = row >> 7;
            const int pos = atomicAdd(&cnt[bk], 1);
            int2 v;
            v.x = ((row & 127) << 17) | ecol[e];   // col < 2^17
            v.y = __float_as_int(ew[e]);
            csr[(size_t)bk * CAP + base[bk] + pos] = v;
        }
    }
}

// ---------------- bucket gather: LDS counting sort + register gather --------
// 512 threads/block (grid fixed at 782 -> 3 blocks/CU; wider block = more
// resident waves for latency hiding on random h reads).
__global__ __launch_bounds__(512)
void bgather_kernel(const unsigned short* __restrict__ h,
                    const int* __restrict__ bcnt,
                    const int2* __restrict__ csr, float* __restrict__ out) {
    __shared__ int2 se[CAP];            // sorted edges
    __shared__ int  s_cnt[BROWS];       // histogram -> cursor
    __shared__ int  s_start[BROWS + 1];
    __shared__ int  wtot;
    const int b = blockIdx.x, t = threadIdx.x;
    const int n = bcnt[b];
    const int2* ebase = csr + (size_t)b * CAP;

    if (t < BROWS) s_cnt[t] = 0;
    __syncthreads();
    // pass 1: histogram by row-offset
    for (int j = t; j < n; j += 512)
        atomicAdd(&s_cnt[((unsigned)ebase[j].x) >> 17], 1);
    __syncthreads();
    // scan 128 bins
    const int lane = t & 63;
    int c = 0;
    if (t < BROWS) c = s_cnt[t];
    int v = c;
#pragma unroll
    for (int off = 1; off < 64; off <<= 1) {
        const int nn = __shfl_up(v, off, 64);
        if (lane >= off) v += nn;
    }
    if (t == 63) wtot = v;
    __syncthreads();
    if (t < BROWS) {
        const int excl = v - c + (t >= 64 ? wtot : 0);
        s_start[t] = excl;
        s_cnt[t]   = excl;   // reuse as scatter cursor
    }
    if (t == 0) s_start[BROWS] = n;
    __syncthreads();
    // pass 2: scatter into row-sorted order
    for (int j = t; j < n; j += 512) {
        const int2 cw  = ebase[j];
        const int  pos = atomicAdd(&s_cnt[((unsigned)cw.x) >> 17], 1);
        se[pos] = cw;
    }
    __syncthreads();

    // gather: 32 groups of 16 lanes; group g handles rows g, g+32, g+64, g+96
    const int l16 = t & 15, g = t >> 4;
    const int row0 = b * BROWS;
#pragma unroll
    for (int rp = 0; rp < 4; ++rp) {
        const int r  = rp * 32 + g;
        const int gr = row0 + r;
        const int rs = s_start[r], re = s_start[r + 1];
        float acc[8];
#pragma unroll
        for (int i = 0; i < 8; ++i) acc[i] = 0.f;
        int j = rs;
        for (; j + 2 <= re; j += 2) {
            const int2 cw0 = se[j], cw1 = se[j + 1];
            const float w0 = __int_as_float(cw0.y);
            const float w1 = __int_as_float(cw1.y);
            const uint4 q0 = *(const uint4*)(h + (size_t)(cw0.x & 0x1FFFF) * DO + l16 * 8);
            const uint4 q1 = *(const uint4*)(h + (size_t)(cw1.x & 0x1FFFF) * DO + l16 * 8);
            const unsigned* u0 = (const unsigned*)&q0;
            const unsigned* u1 = (const unsigned*)&q1;
#pragma unroll
            for (int i = 0; i < 4; ++i) {
                acc[2 * i + 0] += w0 * bf2f(u0[i] & 0xFFFF) + w1 * bf2f(u1[i] & 0xFFFF);
                acc[2 * i + 1] += w0 * bf2f(u0[i] >> 16)    + w1 * bf2f(u1[i] >> 16);
            }
        }
        if (j < re) {
            const int2 cw = se[j];
            const float w = __int_as_float(cw.y);
            const uint4 q = *(const uint4*)(h + (size_t)(cw.x & 0x1FFFF) * DO + l16 * 8);
            const unsigned* u = (const unsigned*)&q;
#pragma unroll
            for (int i = 0; i < 4; ++i) {
                acc[2 * i + 0] += w * bf2f(u[i] & 0xFFFF);
                acc[2 * i + 1] += w * bf2f(u[i] >> 16);
            }
        }
        if (gr < NN) {
            float* op = out + (size_t)gr * DO + l16 * 8;
            *(float4*)(op + 0) = make_float4(fmaxf(acc[0], 0.f), fmaxf(acc[1], 0.f),
                                             fmaxf(acc[2], 0.f), fmaxf(acc[3], 0.f));
            *(float4*)(op + 4) = make_float4(fmaxf(acc[4], 0.f), fmaxf(acc[5], 0.f),
                                             fmaxf(acc[6], 0.f), fmaxf(acc[7], 0.f));
        }
    }
}

extern "C" void kernel_launch(void* const* d_in, const int* in_sizes, int n_in,
                              void* d_out, int out_size, void* d_ws, size_t ws_size,
                              hipStream_t stream) {
    const float* x    = (const float*)d_in[0];
    const float* mask = (const float*)d_in[1];
    const float* W    = (const float*)d_in[2];
    const int*   erow = (const int*)d_in[3];
    const int*   ecol = (const int*)d_in[4];
    const float* ew   = (const float*)d_in[5];
    float* out = (float*)d_out;

    char* p = (char*)d_ws;
    unsigned short* h  = (unsigned short*)p;  p += (size_t)NN * DO * 2;   // 25.6 MB
    unsigned short* Wt = (unsigned short*)p;  p += (size_t)DO * DI * 2;   // 64 KB
    int* bcnt = (int*)p;                      p += 3200;
    int2* csr = (int2*)p;                     // NBK*CAP*8 = 16.8 MB

    hipMemsetAsync(bcnt, 0, NBK * sizeof(int), stream);

    wt_kernel<<<32, 256, 0, stream>>>(W, Wt);
    gemm_kernel<<<(NN + 63) / 64, 256, 0, stream>>>(x, mask, Wt, h);
    part_kernel<<<(NE + TILE - 1) / TILE, 256, 0, stream>>>(erow, ecol, ew,
                                                            bcnt, csr);
    bgather_kernel<<<NBK, 512, 0, stream>>>(h, bcnt, csr, out);
}